// Round 16
// baseline (102.320 us; speedup 1.0000x reference)
//
#include <hip/hip_runtime.h>
#include <hip/hip_bf16.h>
#include <math.h>

// HyperbolicMLR: out[b,c] = -asinh( 2*sc_diff_a / ((1+diff_norm2)*|a_c|) )
// R16: R14 ring-3 3-block config + cross-barrier fragment pipelining:
// body T: gate vm(4) -> barrier -> stage T+3 -> ds_read frags(T+1) into
// ping-pong set -> MFMA(T) from regs read at body T-1. ds_read latency
// drains under the MFMA burst instead of blocking it.

#define EPSF 1e-15f
#define MAXN 0.99999f   // (1 - 1e-5) / sqrt(c), c = 1

constexpr int Bdim = 4096;
constexpr int Ddim = 1024;
constexpr int Cdim = 4096;

typedef __bf16 bf16x8 __attribute__((ext_vector_type(8)));
typedef float  f32x4  __attribute__((ext_vector_type(4)));
typedef unsigned short u16;

__device__ __forceinline__ u16 f2bf(float f) {
  __hip_bfloat16 h = __float2bfloat16(f);   // RNE
  return *reinterpret_cast<const u16*>(&h);
}

__device__ __forceinline__ void gl_lds16(const u16* g, u16* l) {
  __builtin_amdgcn_global_load_lds(
      (const __attribute__((address_space(1))) void*)g,
      (__attribute__((address_space(3))) void*)l, 16, 0, 0);
}

// ---------------- prep kernels (unchanged, proven) ----------------

__global__ __launch_bounds__(256) void prep_x(const float* __restrict__ x,
                                              u16* __restrict__ xb,
                                              float* __restrict__ x2o) {
  const int b = blockIdx.x, t = threadIdx.x;
  float4 v = ((const float4*)(x + (size_t)b * Ddim))[t];
  float s = v.x * v.x + v.y * v.y + v.z * v.z + v.w * v.w;
  __shared__ float red[4];
#pragma unroll
  for (int o = 32; o > 0; o >>= 1) s += __shfl_down(s, o);
  if ((t & 63) == 0) red[t >> 6] = s;
  __syncthreads();
  s = red[0] + red[1] + red[2] + red[3];
  float norm  = sqrtf(s);
  float xn    = fmaxf(norm, EPSF);
  float scale = (xn > MAXN) ? (MAXN / xn) : 1.0f;
  if (t == 0) x2o[b] = s * scale * scale;
  ushort4 o4;
  o4.x = f2bf(v.x * scale); o4.y = f2bf(v.y * scale);
  o4.z = f2bf(v.z * scale); o4.w = f2bf(v.w * scale);
  ((ushort4*)(xb + (size_t)b * Ddim))[t] = o4;
}

// P row c -> PA row ((c>>4)<<5)+(c&15); A row c -> +16 (16-row interleave).
// Stores ani = 1/|a_c|.
__global__ __launch_bounds__(256) void prep_pa(const float* __restrict__ a,
                                               const float* __restrict__ p,
                                               u16* __restrict__ pab,
                                               float* __restrict__ p2o,
                                               float* __restrict__ pao,
                                               float* __restrict__ anio) {
  const int c = blockIdx.x, t = threadIdx.x;
  float4 av = ((const float4*)(a + (size_t)c * Ddim))[t];
  float4 pv = ((const float4*)(p + (size_t)c * Ddim))[t];
  float sp2 = pv.x * pv.x + pv.y * pv.y + pv.z * pv.z + pv.w * pv.w;
  float spa = pv.x * av.x + pv.y * av.y + pv.z * av.z + pv.w * av.w;
  float sa2 = av.x * av.x + av.y * av.y + av.z * av.z + av.w * av.w;
  __shared__ float red[12];
#pragma unroll
  for (int o = 32; o > 0; o >>= 1) {
    sp2 += __shfl_down(sp2, o);
    spa += __shfl_down(spa, o);
    sa2 += __shfl_down(sa2, o);
  }
  if ((t & 63) == 0) { int w = t >> 6; red[w] = sp2; red[4 + w] = spa; red[8 + w] = sa2; }
  __syncthreads();
  if (t == 0) {
    p2o[c]  = red[0] + red[1] + red[2] + red[3];
    pao[c]  = red[4] + red[5] + red[6] + red[7];
    anio[c] = 1.0f / sqrtf(red[8] + red[9] + red[10] + red[11]);
  }
  const int prP = ((c >> 4) << 5) + (c & 15);
  ushort4 oa, op;
  oa.x = f2bf(av.x); oa.y = f2bf(av.y); oa.z = f2bf(av.z); oa.w = f2bf(av.w);
  op.x = f2bf(pv.x); op.y = f2bf(pv.y); op.z = f2bf(pv.z); op.w = f2bf(pv.w);
  ((ushort4*)(pab + (size_t)prP * Ddim))[t]        = op;
  ((ushort4*)(pab + (size_t)(prP + 16) * Ddim))[t] = oa;
}

// ---------------- fused GEMM + epilogue ----------------
// Block: 256 thr / 4 waves (2x2). Tile 128 X-rows x 128 PA-rows, BK=32.
// Per wave: out 64x64-PA, acc[4][4]; 8 b128 reads + 16 MFMA per tile.
// LDS: ring-3 x (X 8KB + PA 8KB) = 48 KB -> 3 blocks/CU.

__global__ __launch_bounds__(256, 3) void gemm_ep(
    const u16* __restrict__ xb, const u16* __restrict__ pab,
    const float* __restrict__ x2g, const float* __restrict__ p2g,
    const float* __restrict__ pag, const float* __restrict__ anig,
    float* __restrict__ out) {
  __shared__ u16 Xs[3][4096];      // [slot][128 rows x 32 u16] = 24 KiB
  __shared__ u16 PAs[3][4096];     // [slot][128 rows x 32 u16] = 24 KiB

  const int t = threadIdx.x;       // 0..255

  // XCD-aware bijective swizzle: 2048 blocks = 8 chunks x 256
  const int flat  = blockIdx.y * 64 + blockIdx.x;
  const int swz   = (flat & 7) * 256 + (flat >> 3);
  const int chunk = swz >> 8;                  // 0..7
  const int local = swz & 255;
  const int bx = chunk * 8 + (local & 7);      // 0..63  PA col-group (128 PA rows)
  const int by = local >> 3;                   // 0..31  X row-group (128 rows)

  const int lane = t & 63;
  const int wid  = t >> 6;       // 0..3
  const int wr   = wid >> 1;     // 0..1  (X 64-row half)
  const int wc   = wid & 1;      // 0..1  (PA 64-row half)

  // staging: thread t covers (r0 = t>>2, slot = t&3) of a 64-row unit;
  // source k-chunk pre-swizzled (XOR involution, rule 21 both-sides).
  const int r0  = t >> 2;                              // 0..63
  const int sw8 = ((t & 3) ^ ((r0 >> 1) & 3)) * 8;     // u16
  const u16* xsrc  = xb  + (size_t)(by * 128 + r0) * Ddim + sw8;
  const u16* pasrc = pab + (size_t)(bx * 128 + r0) * Ddim + sw8;
  const int t8 = t * 8;
  const size_t q64 = (size_t)64 * Ddim;     // 64-row stride in source

  // fragment read offsets (u16 units): row*32 + swizzled slot*8
  const int arow = wr * 64 + (lane & 15);
  const int brow = wc * 64 + (lane & 15);
  const int aoff = arow * 32 + (((lane >> 4) ^ ((arow >> 1) & 3)) * 8);
  const int boff = brow * 32 + (((lane >> 4) ^ ((brow >> 1) & 3)) * 8);

  f32x4 acc[4][4];
  const f32x4 zero = {0.f, 0.f, 0.f, 0.f};
#pragma unroll
  for (int m = 0; m < 4; ++m)
#pragma unroll
    for (int n = 0; n < 4; ++n) acc[m][n] = zero;

  struct FragSet { bf16x8 av0, av1, av2, av3, bv0, bv1, bv2, bv3; };
  FragSet fsA, fsB;

#define STAGE(SLOT) do {                                              \
    u16* Xw  = (u16*)&Xs[(SLOT)][0];                                  \
    u16* PAw = (u16*)&PAs[(SLOT)][0];                                 \
    gl_lds16(xgp,            Xw + t8);                                \
    gl_lds16(xgp + q64,      Xw + 2048 + t8);                         \
    gl_lds16(pgp,            PAw + t8);                               \
    gl_lds16(pgp + q64,      PAw + 2048 + t8);                        \
    xgp += 32; pgp += 32;                                             \
  } while (0)

#define READF(FS, SLOT) do {                                          \
    const u16* Xr  = &Xs[(SLOT)][0];                                  \
    const u16* PAr = &PAs[(SLOT)][0];                                 \
    FS.bv0 = *(const bf16x8*)&PAr[boff];                              \
    FS.bv1 = *(const bf16x8*)&PAr[boff + 512];                        \
    FS.bv2 = *(const bf16x8*)&PAr[boff + 1024];                       \
    FS.bv3 = *(const bf16x8*)&PAr[boff + 1536];                       \
    FS.av0 = *(const bf16x8*)&Xr[aoff];                               \
    FS.av1 = *(const bf16x8*)&Xr[aoff + 512];                         \
    FS.av2 = *(const bf16x8*)&Xr[aoff + 1024];                        \
    FS.av3 = *(const bf16x8*)&Xr[aoff + 1536];                        \
  } while (0)

#define MFMA16(FS) do {                                               \
    __builtin_amdgcn_s_setprio(1);                                    \
    _Pragma("unroll")                                                 \
    for (int n = 0; n < 4; ++n) {                                     \
      bf16x8 bv = (n == 0) ? FS.bv0 : (n == 1) ? FS.bv1 : (n == 2) ? FS.bv2 : FS.bv3; \
      acc[0][n] = __builtin_amdgcn_mfma_f32_16x16x32_bf16(FS.av0, bv, acc[0][n], 0, 0, 0); \
      acc[1][n] = __builtin_amdgcn_mfma_f32_16x16x32_bf16(FS.av1, bv, acc[1][n], 0, 0, 0); \
      acc[2][n] = __builtin_amdgcn_mfma_f32_16x16x32_bf16(FS.av2, bv, acc[2][n], 0, 0, 0); \
      acc[3][n] = __builtin_amdgcn_mfma_f32_16x16x32_bf16(FS.av3, bv, acc[3][n], 0, 0, 0); \
    }                                                                 \
    __builtin_amdgcn_s_setprio(0);                                    \
  } while (0)

#define GATE_BAR(N) do {                                              \
    asm volatile("s_waitcnt vmcnt(" #N ")" ::: "memory");             \
    __builtin_amdgcn_s_barrier();                                     \
    __builtin_amdgcn_sched_barrier(0);                                \
  } while (0)

  // BODY(T): gate -> barrier -> stage T+3 (slot T%3) -> read frags T+1
  // (slot (T+1)%3) -> MFMA tile T (regs read at body T-1).
#define BODY(CUR, NXT, RS, SS, DOSTAGE, GATEN) do {                   \
    GATE_BAR(GATEN);                                                  \
    if (DOSTAGE) STAGE(SS);                                           \
    READF(NXT, RS);                                                   \
    MFMA16(CUR);                                                      \
  } while (0)

  // ---- prologue: stage tiles 0,1,2; wait tile 0; read frags(0) -> fsA
  const u16* xgp = xsrc;
  const u16* pgp = pasrc;
  STAGE(0);
  STAGE(1);
  STAGE(2);
  asm volatile("s_waitcnt vmcnt(8)" ::: "memory");   // tile 0 landed
  __builtin_amdgcn_s_barrier();
  __builtin_amdgcn_sched_barrier(0);
  READF(fsA, 0);

  // ---- main: bodies T=0..23 (6-periodic: slot ring x set ping-pong)
  for (int g = 0; g < 4; ++g) {
    BODY(fsA, fsB, 1, 0, 1, 4);      // T=6g+0
    BODY(fsB, fsA, 2, 1, 1, 4);      // T=6g+1
    BODY(fsA, fsB, 0, 2, 1, 4);      // T=6g+2
    BODY(fsB, fsA, 1, 0, 1, 4);      // T=6g+3
    BODY(fsA, fsB, 2, 1, 1, 4);      // T=6g+4
    BODY(fsB, fsA, 0, 2, 1, 4);      // T=6g+5
  }
  // ---- T=24..28 (stage tiles 27..31)
  BODY(fsA, fsB, 1, 0, 1, 4);        // T=24
  BODY(fsB, fsA, 2, 1, 1, 4);        // T=25
  BODY(fsA, fsB, 0, 2, 1, 4);        // T=26
  BODY(fsB, fsA, 1, 0, 1, 4);        // T=27
  BODY(fsA, fsB, 2, 1, 1, 4);        // T=28 (stages tile 31)
  // ---- tail: T=29 (tile 30 retired via vm(4)), T=30 (vm(0)), T=31
  BODY(fsB, fsA, 0, 0, 0, 4);        // T=29: read frags(30)
  BODY(fsA, fsB, 1, 0, 0, 0);        // T=30: read frags(31)
  MFMA16(fsB);                       // T=31

#undef BODY
#undef GATE_BAR
#undef MFMA16
#undef READF
#undef STAGE

  // ---- epilogue: C/D layout col = lane&15, row = (lane>>4)*4 + j.
  // n even -> px, n odd -> xa, same 16 output cols per (even,odd) pair.
  // rcp-based; asinh = 7th-order odd poly (|z| <= ~0.14 -> err ~1e-7).
#pragma unroll
  for (int m = 0; m < 4; ++m) {
    const int rl0 = by * 128 + wr * 64 + m * 16 + (lane >> 4) * 4;
    const float4 x2r4 = *(const float4*)&x2g[rl0];
    float x2r[4] = {x2r4.x, x2r4.y, x2r4.z, x2r4.w};
#pragma unroll
    for (int g = 0; g < 2; ++g) {
      const int cl = bx * 64 + wc * 32 + g * 16 + (lane & 15);
      const float p2c = p2g[cl];
      const float pac = pag[cl];
      const float ani = anig[cl];
      const float Bcc = 1.0f - p2c;
      f32x4 px4 = acc[m][2 * g];
      f32x4 xa4 = acc[m][2 * g + 1];
#pragma unroll
      for (int j = 0; j < 4; ++j) {
        const float px = px4[j];
        const float xa = xa4[j];
        const float Av   = 1.0f - 2.0f * px + x2r[j];
        const float den  = fmaxf(1.0f - 2.0f * px + x2r[j] * p2c, EPSF);
        const float rden = __builtin_amdgcn_rcpf(den);
        const float dn2  = fmaxf((Av * Av * p2c + Bcc * Bcc * x2r[j] - 2.0f * Av * Bcc * px) * rden * rden, EPSF);
        const float sc   = (Bcc * xa - Av * pac) * rden;
        const float z    = 2.0f * sc * ani * __builtin_amdgcn_rcpf(1.0f + dn2);
        const float z2 = z * z;
        // asinh(z) = z(1 - z^2/6 + 3z^4/40 - 15z^6/336), |z|<=0.14
        const float r = z * (1.0f - z2 * (1.0f / 6.0f)
                             + z2 * z2 * (0.075f - z2 * (15.0f / 336.0f)));
        out[(size_t)rl0 * Cdim + j * Cdim + cl] = -r;
      }
    }
  }
}

extern "C" void kernel_launch(void* const* d_in, const int* in_sizes, int n_in,
                              void* d_out, int out_size, void* d_ws, size_t ws_size,
                              hipStream_t stream) {
  const float* x = (const float*)d_in[0];
  const float* a = (const float*)d_in[1];
  const float* p = (const float*)d_in[2];
  float* out = (float*)d_out;

  char* ws = (char*)d_ws;
  u16* xb  = (u16*)(ws);                                  // 8 MiB
  u16* pab = (u16*)(ws + (size_t)8 * 1024 * 1024);        // 16 MiB
  float* x2  = (float*)(ws + (size_t)24 * 1024 * 1024);   // stats
  float* p2  = x2 + Bdim;
  float* pa  = p2 + Cdim;
  float* ani = pa + Cdim;

  prep_x <<<Bdim, 256, 0, stream>>>(x, xb, x2);
  prep_pa<<<Cdim, 256, 0, stream>>>(a, p, pab, p2, pa, ani);
  gemm_ep<<<dim3(64, 32), 256, 0, stream>>>(xb, pab, x2, p2, pa, ani, out);
}

// Round 17
// 101.322 us; speedup vs baseline: 1.0098x; 1.0098x over previous
//
#include <hip/hip_runtime.h>
#include <hip/hip_bf16.h>
#include <math.h>

// HyperbolicMLR: out[b,c] = -asinh( 2*sc_diff_a / ((1+diff_norm2)*|a_c|) )
// R17: R15 gemm (equal-best, 4 blocks/CU) + prep_x/prep_pa FUSED into one
// kernel (removes one launch + stream serialization of two memory-bound
// passes). Everything else unchanged.

#define EPSF 1e-15f
#define MAXN 0.99999f   // (1 - 1e-5) / sqrt(c), c = 1

constexpr int Bdim = 4096;
constexpr int Ddim = 1024;
constexpr int Cdim = 4096;

typedef __bf16 bf16x8 __attribute__((ext_vector_type(8)));
typedef float  f32x4  __attribute__((ext_vector_type(4)));
typedef unsigned short u16;

__device__ __forceinline__ u16 f2bf(float f) {
  __hip_bfloat16 h = __float2bfloat16(f);   // RNE
  return *reinterpret_cast<const u16*>(&h);
}

__device__ __forceinline__ void gl_lds16(const u16* g, u16* l) {
  __builtin_amdgcn_global_load_lds(
      (const __attribute__((address_space(1))) void*)g,
      (__attribute__((address_space(3))) void*)l, 16, 0, 0);
}

// ---------------- fused prep kernel ----------------
// blocks [0, Bdim): project x-row, write bf16 X, x2.
// blocks [Bdim, Bdim+Cdim): write interleaved PA rows + stats (ani = 1/|a|).

__global__ __launch_bounds__(256) void prep_all(
    const float* __restrict__ x, const float* __restrict__ a,
    const float* __restrict__ p, u16* __restrict__ xb,
    u16* __restrict__ pab, float* __restrict__ x2o,
    float* __restrict__ p2o, float* __restrict__ pao,
    float* __restrict__ anio) {
  __shared__ float red[12];
  const int blk = blockIdx.x, t = threadIdx.x;

  if (blk < Bdim) {
    const int b = blk;
    float4 v = ((const float4*)(x + (size_t)b * Ddim))[t];
    float s = v.x * v.x + v.y * v.y + v.z * v.z + v.w * v.w;
#pragma unroll
    for (int o = 32; o > 0; o >>= 1) s += __shfl_down(s, o);
    if ((t & 63) == 0) red[t >> 6] = s;
    __syncthreads();
    s = red[0] + red[1] + red[2] + red[3];
    float norm  = sqrtf(s);
    float xn    = fmaxf(norm, EPSF);
    float scale = (xn > MAXN) ? (MAXN / xn) : 1.0f;
    if (t == 0) x2o[b] = s * scale * scale;
    ushort4 o4;
    o4.x = f2bf(v.x * scale); o4.y = f2bf(v.y * scale);
    o4.z = f2bf(v.z * scale); o4.w = f2bf(v.w * scale);
    ((ushort4*)(xb + (size_t)b * Ddim))[t] = o4;
  } else {
    const int c = blk - Bdim;
    float4 av = ((const float4*)(a + (size_t)c * Ddim))[t];
    float4 pv = ((const float4*)(p + (size_t)c * Ddim))[t];
    float sp2 = pv.x * pv.x + pv.y * pv.y + pv.z * pv.z + pv.w * pv.w;
    float spa = pv.x * av.x + pv.y * av.y + pv.z * av.z + pv.w * av.w;
    float sa2 = av.x * av.x + av.y * av.y + av.z * av.z + av.w * av.w;
#pragma unroll
    for (int o = 32; o > 0; o >>= 1) {
      sp2 += __shfl_down(sp2, o);
      spa += __shfl_down(spa, o);
      sa2 += __shfl_down(sa2, o);
    }
    if ((t & 63) == 0) { int w = t >> 6; red[w] = sp2; red[4 + w] = spa; red[8 + w] = sa2; }
    __syncthreads();
    if (t == 0) {
      p2o[c]  = red[0] + red[1] + red[2] + red[3];
      pao[c]  = red[4] + red[5] + red[6] + red[7];
      anio[c] = 1.0f / sqrtf(red[8] + red[9] + red[10] + red[11]);
    }
    const int prP = ((c >> 4) << 5) + (c & 15);
    ushort4 oa, op;
    oa.x = f2bf(av.x); oa.y = f2bf(av.y); oa.z = f2bf(av.z); oa.w = f2bf(av.w);
    op.x = f2bf(pv.x); op.y = f2bf(pv.y); op.z = f2bf(pv.z); op.w = f2bf(pv.w);
    ((ushort4*)(pab + (size_t)prP * Ddim))[t]        = op;
    ((ushort4*)(pab + (size_t)(prP + 16) * Ddim))[t] = oa;
  }
}

// ---------------- fused GEMM + epilogue (R15, unchanged) ----------------
// Block: 256 thr / 4 waves (2x2). Tile 128 X-rows x 128 PA-rows, BK=32.
// Per wave: out 64x64-PA, acc[4][4] (64 regs); 8 b128 reads + 16 MFMA / tile.
// LDS: ring-2 x (X 8KB + PA 8KB) = 32 KB -> 4 blocks/CU (with 4 waves/SIMD).

__global__ __launch_bounds__(256, 4) void gemm_ep(
    const u16* __restrict__ xb, const u16* __restrict__ pab,
    const float* __restrict__ x2g, const float* __restrict__ p2g,
    const float* __restrict__ pag, const float* __restrict__ anig,
    float* __restrict__ out) {
  __shared__ u16 Xs[2][4096];      // [slot][128 rows x 32 u16] = 16 KiB
  __shared__ u16 PAs[2][4096];     // [slot][128 rows x 32 u16] = 16 KiB

  const int t = threadIdx.x;       // 0..255

  // XCD-aware bijective swizzle: 2048 blocks = 8 chunks x 256
  const int flat  = blockIdx.y * 64 + blockIdx.x;
  const int swz   = (flat & 7) * 256 + (flat >> 3);
  const int chunk = swz >> 8;                  // 0..7
  const int local = swz & 255;
  const int bx = chunk * 8 + (local & 7);      // 0..63  PA col-group (128 PA rows)
  const int by = local >> 3;                   // 0..31  X row-group (128 rows)

  const int lane = t & 63;
  const int wid  = t >> 6;       // 0..3
  const int wr   = wid >> 1;     // 0..1  (X 64-row half)
  const int wc   = wid & 1;      // 0..1  (PA 64-row half)

  // staging: thread t covers (r0 = t>>2, slot = t&3) of a 64-row unit;
  // source k-chunk pre-swizzled (XOR involution, rule 21 both-sides).
  const int r0  = t >> 2;                              // 0..63
  const int sw8 = ((t & 3) ^ ((r0 >> 1) & 3)) * 8;     // u16
  const u16* xsrc  = xb  + (size_t)(by * 128 + r0) * Ddim + sw8;
  const u16* pasrc = pab + (size_t)(bx * 128 + r0) * Ddim + sw8;
  const int t8 = t * 8;
  const size_t q64 = (size_t)64 * Ddim;     // 64-row stride in source

  // fragment read offsets (u16 units): row*32 + swizzled slot*8
  const int arow = wr * 64 + (lane & 15);
  const int brow = wc * 64 + (lane & 15);
  const int aoff = arow * 32 + (((lane >> 4) ^ ((arow >> 1) & 3)) * 8);
  const int boff = brow * 32 + (((lane >> 4) ^ ((brow >> 1) & 3)) * 8);

  f32x4 acc[4][4];
  const f32x4 zero = {0.f, 0.f, 0.f, 0.f};
#pragma unroll
  for (int m = 0; m < 4; ++m)
#pragma unroll
    for (int n = 0; n < 4; ++n) acc[m][n] = zero;

#define STAGE(SLOT) do {                                              \
    u16* Xw  = (u16*)&Xs[(SLOT)][0];                                  \
    u16* PAw = (u16*)&PAs[(SLOT)][0];                                 \
    gl_lds16(xgp,            Xw + t8);                                \
    gl_lds16(xgp + q64,      Xw + 2048 + t8);                         \
    gl_lds16(pgp,            PAw + t8);                               \
    gl_lds16(pgp + q64,      PAw + 2048 + t8);                        \
    xgp += 32; pgp += 32;                                             \
  } while (0)

#define COMPUTE(SLOT) do {                                            \
    const u16* Xr  = &Xs[(SLOT)][0];                                  \
    const u16* PAr = &PAs[(SLOT)][0];                                 \
    bf16x8 bv0 = *(const bf16x8*)&PAr[boff];                          \
    bf16x8 bv1 = *(const bf16x8*)&PAr[boff + 512];                    \
    bf16x8 bv2 = *(const bf16x8*)&PAr[boff + 1024];                   \
    bf16x8 bv3 = *(const bf16x8*)&PAr[boff + 1536];                   \
    bf16x8 a0 = *(const bf16x8*)&Xr[aoff];                            \
    bf16x8 a1 = *(const bf16x8*)&Xr[aoff + 512];                      \
    bf16x8 a2 = *(const bf16x8*)&Xr[aoff + 1024];                     \
    bf16x8 a3 = *(const bf16x8*)&Xr[aoff + 1536];                     \
    __builtin_amdgcn_s_setprio(1);                                    \
    _Pragma("unroll")                                                 \
    for (int n = 0; n < 4; ++n) {                                     \
      bf16x8 bv = (n == 0) ? bv0 : (n == 1) ? bv1 : (n == 2) ? bv2 : bv3; \
      acc[0][n] = __builtin_amdgcn_mfma_f32_16x16x32_bf16(a0, bv, acc[0][n], 0, 0, 0); \
      acc[1][n] = __builtin_amdgcn_mfma_f32_16x16x32_bf16(a1, bv, acc[1][n], 0, 0, 0); \
      acc[2][n] = __builtin_amdgcn_mfma_f32_16x16x32_bf16(a2, bv, acc[2][n], 0, 0, 0); \
      acc[3][n] = __builtin_amdgcn_mfma_f32_16x16x32_bf16(a3, bv, acc[3][n], 0, 0, 0); \
    }                                                                 \
    __builtin_amdgcn_s_setprio(0);                                    \
  } while (0)

#define GATE_BAR(N) do {                                              \
    asm volatile("s_waitcnt vmcnt(" #N ")" ::: "memory");             \
    __builtin_amdgcn_s_barrier();                                     \
    __builtin_amdgcn_sched_barrier(0);                                \
  } while (0)

  // ---- prologue: stage tile 0 into slot 0
  const u16* xgp = xsrc;
  const u16* pgp = pasrc;
  STAGE(0);

  // ---- main loop: per tile T: gate vmcnt(0) [T's 4 loads landed; they are
  // the only outstanding ones] -> barrier -> STAGE(T+1, other slot; that
  // slot's reads all happened before this barrier: WAR-safe) -> COMPUTE(T).
  for (int g = 0; g < 15; ++g) {
    GATE_BAR(0);  STAGE(1);  COMPUTE(0);     // T=2g
    GATE_BAR(0);  STAGE(0);  COMPUTE(1);     // T=2g+1
  }
  // ---- T=30 (stages tile 31), T=31 (no stage)
  GATE_BAR(0);  STAGE(1);  COMPUTE(0);
  GATE_BAR(0);  COMPUTE(1);

#undef GATE_BAR
#undef STAGE
#undef COMPUTE

  // ---- epilogue: C/D layout col = lane&15, row = (lane>>4)*4 + j.
  // n even -> px, n odd -> xa, same 16 output cols per (even,odd) pair.
  // rcp-based; asinh = 7th-order odd poly (|z| <= ~0.14 -> err ~1e-7).
#pragma unroll
  for (int m = 0; m < 4; ++m) {
    const int rl0 = by * 128 + wr * 64 + m * 16 + (lane >> 4) * 4;
    const float4 x2r4 = *(const float4*)&x2g[rl0];
    float x2r[4] = {x2r4.x, x2r4.y, x2r4.z, x2r4.w};
#pragma unroll
    for (int g = 0; g < 2; ++g) {
      const int cl = bx * 64 + wc * 32 + g * 16 + (lane & 15);
      const float p2c = p2g[cl];
      const float pac = pag[cl];
      const float ani = anig[cl];
      const float Bcc = 1.0f - p2c;
      f32x4 px4 = acc[m][2 * g];
      f32x4 xa4 = acc[m][2 * g + 1];
#pragma unroll
      for (int j = 0; j < 4; ++j) {
        const float px = px4[j];
        const float xa = xa4[j];
        const float Av   = 1.0f - 2.0f * px + x2r[j];
        const float den  = fmaxf(1.0f - 2.0f * px + x2r[j] * p2c, EPSF);
        const float rden = __builtin_amdgcn_rcpf(den);
        const float dn2  = fmaxf((Av * Av * p2c + Bcc * Bcc * x2r[j] - 2.0f * Av * Bcc * px) * rden * rden, EPSF);
        const float sc   = (Bcc * xa - Av * pac) * rden;
        const float z    = 2.0f * sc * ani * __builtin_amdgcn_rcpf(1.0f + dn2);
        const float z2 = z * z;
        // asinh(z) = z(1 - z^2/6 + 3z^4/40 - 15z^6/336), |z|<=0.14
        const float r = z * (1.0f - z2 * (1.0f / 6.0f)
                             + z2 * z2 * (0.075f - z2 * (15.0f / 336.0f)));
        out[(size_t)rl0 * Cdim + j * Cdim + cl] = -r;
      }
    }
  }
}

extern "C" void kernel_launch(void* const* d_in, const int* in_sizes, int n_in,
                              void* d_out, int out_size, void* d_ws, size_t ws_size,
                              hipStream_t stream) {
  const float* x = (const float*)d_in[0];
  const float* a = (const float*)d_in[1];
  const float* p = (const float*)d_in[2];
  float* out = (float*)d_out;

  char* ws = (char*)d_ws;
  u16* xb  = (u16*)(ws);                                  // 8 MiB
  u16* pab = (u16*)(ws + (size_t)8 * 1024 * 1024);        // 16 MiB
  float* x2  = (float*)(ws + (size_t)24 * 1024 * 1024);   // stats
  float* p2  = x2 + Bdim;
  float* pa  = p2 + Cdim;
  float* ani = pa + Cdim;

  prep_all<<<Bdim + Cdim, 256, 0, stream>>>(x, a, p, xb, pab, x2, p2, pa, ani);
  gemm_ep<<<dim3(64, 32), 256, 0, stream>>>(xb, pab, x2, p2, pa, ani, out);
}

// Round 18
// 100.943 us; speedup vs baseline: 1.0136x; 1.0038x over previous
//
#include <hip/hip_runtime.h>
#include <hip/hip_bf16.h>
#include <math.h>

// HyperbolicMLR: out[b,c] = -asinh( 2*sc_diff_a / ((1+diff_norm2)*|a_c|) )
// R18: R17 + __builtin_nontemporal_store on the output stream. The 64MB
// out-writes were flowing through L2/L3 and evicting the 24MB operand
// panels (FETCH_SIZE 51.5MB >> 24MB) -> staging loads missed to HBM
// (~900cy) and stalled the per-tile vmcnt gates. nt stores keep operands
// cache-resident. Single-variable A/B vs R17.

#define EPSF 1e-15f
#define MAXN 0.99999f   // (1 - 1e-5) / sqrt(c), c = 1

constexpr int Bdim = 4096;
constexpr int Ddim = 1024;
constexpr int Cdim = 4096;

typedef __bf16 bf16x8 __attribute__((ext_vector_type(8)));
typedef float  f32x4  __attribute__((ext_vector_type(4)));
typedef unsigned short u16;

__device__ __forceinline__ u16 f2bf(float f) {
  __hip_bfloat16 h = __float2bfloat16(f);   // RNE
  return *reinterpret_cast<const u16*>(&h);
}

__device__ __forceinline__ void gl_lds16(const u16* g, u16* l) {
  __builtin_amdgcn_global_load_lds(
      (const __attribute__((address_space(1))) void*)g,
      (__attribute__((address_space(3))) void*)l, 16, 0, 0);
}

// ---------------- fused prep kernel (R17, unchanged) ----------------

__global__ __launch_bounds__(256) void prep_all(
    const float* __restrict__ x, const float* __restrict__ a,
    const float* __restrict__ p, u16* __restrict__ xb,
    u16* __restrict__ pab, float* __restrict__ x2o,
    float* __restrict__ p2o, float* __restrict__ pao,
    float* __restrict__ anio) {
  __shared__ float red[12];
  const int blk = blockIdx.x, t = threadIdx.x;

  if (blk < Bdim) {
    const int b = blk;
    float4 v = ((const float4*)(x + (size_t)b * Ddim))[t];
    float s = v.x * v.x + v.y * v.y + v.z * v.z + v.w * v.w;
#pragma unroll
    for (int o = 32; o > 0; o >>= 1) s += __shfl_down(s, o);
    if ((t & 63) == 0) red[t >> 6] = s;
    __syncthreads();
    s = red[0] + red[1] + red[2] + red[3];
    float norm  = sqrtf(s);
    float xn    = fmaxf(norm, EPSF);
    float scale = (xn > MAXN) ? (MAXN / xn) : 1.0f;
    if (t == 0) x2o[b] = s * scale * scale;
    ushort4 o4;
    o4.x = f2bf(v.x * scale); o4.y = f2bf(v.y * scale);
    o4.z = f2bf(v.z * scale); o4.w = f2bf(v.w * scale);
    ((ushort4*)(xb + (size_t)b * Ddim))[t] = o4;
  } else {
    const int c = blk - Bdim;
    float4 av = ((const float4*)(a + (size_t)c * Ddim))[t];
    float4 pv = ((const float4*)(p + (size_t)c * Ddim))[t];
    float sp2 = pv.x * pv.x + pv.y * pv.y + pv.z * pv.z + pv.w * pv.w;
    float spa = pv.x * av.x + pv.y * av.y + pv.z * av.z + pv.w * av.w;
    float sa2 = av.x * av.x + av.y * av.y + av.z * av.z + av.w * av.w;
#pragma unroll
    for (int o = 32; o > 0; o >>= 1) {
      sp2 += __shfl_down(sp2, o);
      spa += __shfl_down(spa, o);
      sa2 += __shfl_down(sa2, o);
    }
    if ((t & 63) == 0) { int w = t >> 6; red[w] = sp2; red[4 + w] = spa; red[8 + w] = sa2; }
    __syncthreads();
    if (t == 0) {
      p2o[c]  = red[0] + red[1] + red[2] + red[3];
      pao[c]  = red[4] + red[5] + red[6] + red[7];
      anio[c] = 1.0f / sqrtf(red[8] + red[9] + red[10] + red[11]);
    }
    const int prP = ((c >> 4) << 5) + (c & 15);
    ushort4 oa, op;
    oa.x = f2bf(av.x); oa.y = f2bf(av.y); oa.z = f2bf(av.z); oa.w = f2bf(av.w);
    op.x = f2bf(pv.x); op.y = f2bf(pv.y); op.z = f2bf(pv.z); op.w = f2bf(pv.w);
    ((ushort4*)(pab + (size_t)prP * Ddim))[t]        = op;
    ((ushort4*)(pab + (size_t)(prP + 16) * Ddim))[t] = oa;
  }
}

// ---------------- fused GEMM + epilogue (R15 + nt stores) ----------------
// Block: 256 thr / 4 waves (2x2). Tile 128 X-rows x 128 PA-rows, BK=32.
// Per wave: out 64x64-PA, acc[4][4] (64 regs); 8 b128 reads + 16 MFMA / tile.
// LDS: ring-2 x (X 8KB + PA 8KB) = 32 KB -> 4 blocks/CU (with 4 waves/SIMD).

__global__ __launch_bounds__(256, 4) void gemm_ep(
    const u16* __restrict__ xb, const u16* __restrict__ pab,
    const float* __restrict__ x2g, const float* __restrict__ p2g,
    const float* __restrict__ pag, const float* __restrict__ anig,
    float* __restrict__ out) {
  __shared__ u16 Xs[2][4096];      // [slot][128 rows x 32 u16] = 16 KiB
  __shared__ u16 PAs[2][4096];     // [slot][128 rows x 32 u16] = 16 KiB

  const int t = threadIdx.x;       // 0..255

  // XCD-aware bijective swizzle: 2048 blocks = 8 chunks x 256
  const int flat  = blockIdx.y * 64 + blockIdx.x;
  const int swz   = (flat & 7) * 256 + (flat >> 3);
  const int chunk = swz >> 8;                  // 0..7
  const int local = swz & 255;
  const int bx = chunk * 8 + (local & 7);      // 0..63  PA col-group (128 PA rows)
  const int by = local >> 3;                   // 0..31  X row-group (128 rows)

  const int lane = t & 63;
  const int wid  = t >> 6;       // 0..3
  const int wr   = wid >> 1;     // 0..1  (X 64-row half)
  const int wc   = wid & 1;      // 0..1  (PA 64-row half)

  // staging: thread t covers (r0 = t>>2, slot = t&3) of a 64-row unit;
  // source k-chunk pre-swizzled (XOR involution, rule 21 both-sides).
  const int r0  = t >> 2;                              // 0..63
  const int sw8 = ((t & 3) ^ ((r0 >> 1) & 3)) * 8;     // u16
  const u16* xsrc  = xb  + (size_t)(by * 128 + r0) * Ddim + sw8;
  const u16* pasrc = pab + (size_t)(bx * 128 + r0) * Ddim + sw8;
  const int t8 = t * 8;
  const size_t q64 = (size_t)64 * Ddim;     // 64-row stride in source

  // fragment read offsets (u16 units): row*32 + swizzled slot*8
  const int arow = wr * 64 + (lane & 15);
  const int brow = wc * 64 + (lane & 15);
  const int aoff = arow * 32 + (((lane >> 4) ^ ((arow >> 1) & 3)) * 8);
  const int boff = brow * 32 + (((lane >> 4) ^ ((brow >> 1) & 3)) * 8);

  f32x4 acc[4][4];
  const f32x4 zero = {0.f, 0.f, 0.f, 0.f};
#pragma unroll
  for (int m = 0; m < 4; ++m)
#pragma unroll
    for (int n = 0; n < 4; ++n) acc[m][n] = zero;

#define STAGE(SLOT) do {                                              \
    u16* Xw  = (u16*)&Xs[(SLOT)][0];                                  \
    u16* PAw = (u16*)&PAs[(SLOT)][0];                                 \
    gl_lds16(xgp,            Xw + t8);                                \
    gl_lds16(xgp + q64,      Xw + 2048 + t8);                         \
    gl_lds16(pgp,            PAw + t8);                               \
    gl_lds16(pgp + q64,      PAw + 2048 + t8);                        \
    xgp += 32; pgp += 32;                                             \
  } while (0)

#define COMPUTE(SLOT) do {                                            \
    const u16* Xr  = &Xs[(SLOT)][0];                                  \
    const u16* PAr = &PAs[(SLOT)][0];                                 \
    bf16x8 bv0 = *(const bf16x8*)&PAr[boff];                          \
    bf16x8 bv1 = *(const bf16x8*)&PAr[boff + 512];                    \
    bf16x8 bv2 = *(const bf16x8*)&PAr[boff + 1024];                   \
    bf16x8 bv3 = *(const bf16x8*)&PAr[boff + 1536];                   \
    bf16x8 a0 = *(const bf16x8*)&Xr[aoff];                            \
    bf16x8 a1 = *(const bf16x8*)&Xr[aoff + 512];                      \
    bf16x8 a2 = *(const bf16x8*)&Xr[aoff + 1024];                     \
    bf16x8 a3 = *(const bf16x8*)&Xr[aoff + 1536];                     \
    __builtin_amdgcn_s_setprio(1);                                    \
    _Pragma("unroll")                                                 \
    for (int n = 0; n < 4; ++n) {                                     \
      bf16x8 bv = (n == 0) ? bv0 : (n == 1) ? bv1 : (n == 2) ? bv2 : bv3; \
      acc[0][n] = __builtin_amdgcn_mfma_f32_16x16x32_bf16(a0, bv, acc[0][n], 0, 0, 0); \
      acc[1][n] = __builtin_amdgcn_mfma_f32_16x16x32_bf16(a1, bv, acc[1][n], 0, 0, 0); \
      acc[2][n] = __builtin_amdgcn_mfma_f32_16x16x32_bf16(a2, bv, acc[2][n], 0, 0, 0); \
      acc[3][n] = __builtin_amdgcn_mfma_f32_16x16x32_bf16(a3, bv, acc[3][n], 0, 0, 0); \
    }                                                                 \
    __builtin_amdgcn_s_setprio(0);                                    \
  } while (0)

#define GATE_BAR(N) do {                                              \
    asm volatile("s_waitcnt vmcnt(" #N ")" ::: "memory");             \
    __builtin_amdgcn_s_barrier();                                     \
    __builtin_amdgcn_sched_barrier(0);                                \
  } while (0)

  // ---- prologue: stage tile 0 into slot 0
  const u16* xgp = xsrc;
  const u16* pgp = pasrc;
  STAGE(0);

  // ---- main loop: per tile T: gate vmcnt(0) [T's 4 loads landed] ->
  // barrier -> STAGE(T+1, other slot; WAR-safe) -> COMPUTE(T).
  for (int g = 0; g < 15; ++g) {
    GATE_BAR(0);  STAGE(1);  COMPUTE(0);     // T=2g
    GATE_BAR(0);  STAGE(0);  COMPUTE(1);     // T=2g+1
  }
  // ---- T=30 (stages tile 31), T=31 (no stage)
  GATE_BAR(0);  STAGE(1);  COMPUTE(0);
  GATE_BAR(0);  COMPUTE(1);

#undef GATE_BAR
#undef STAGE
#undef COMPUTE

  // ---- epilogue: C/D layout col = lane&15, row = (lane>>4)*4 + j.
  // n even -> px, n odd -> xa, same 16 output cols per (even,odd) pair.
  // rcp-based; asinh = 7th-order odd poly. Output via NONTEMPORAL stores
  // (streaming: don't evict operand panels from L2/L3).
#pragma unroll
  for (int m = 0; m < 4; ++m) {
    const int rl0 = by * 128 + wr * 64 + m * 16 + (lane >> 4) * 4;
    const float4 x2r4 = *(const float4*)&x2g[rl0];
    float x2r[4] = {x2r4.x, x2r4.y, x2r4.z, x2r4.w};
#pragma unroll
    for (int g = 0; g < 2; ++g) {
      const int cl = bx * 64 + wc * 32 + g * 16 + (lane & 15);
      const float p2c = p2g[cl];
      const float pac = pag[cl];
      const float ani = anig[cl];
      const float Bcc = 1.0f - p2c;
      f32x4 px4 = acc[m][2 * g];
      f32x4 xa4 = acc[m][2 * g + 1];
#pragma unroll
      for (int j = 0; j < 4; ++j) {
        const float px = px4[j];
        const float xa = xa4[j];
        const float Av   = 1.0f - 2.0f * px + x2r[j];
        const float den  = fmaxf(1.0f - 2.0f * px + x2r[j] * p2c, EPSF);
        const float rden = __builtin_amdgcn_rcpf(den);
        const float dn2  = fmaxf((Av * Av * p2c + Bcc * Bcc * x2r[j] - 2.0f * Av * Bcc * px) * rden * rden, EPSF);
        const float sc   = (Bcc * xa - Av * pac) * rden;
        const float z    = 2.0f * sc * ani * __builtin_amdgcn_rcpf(1.0f + dn2);
        const float z2 = z * z;
        // asinh(z) = z(1 - z^2/6 + 3z^4/40 - 15z^6/336), |z|<=0.14
        const float r = z * (1.0f - z2 * (1.0f / 6.0f)
                             + z2 * z2 * (0.075f - z2 * (15.0f / 336.0f)));
        __builtin_nontemporal_store(-r, &out[(size_t)rl0 * Cdim + j * Cdim + cl]);
      }
    }
  }
}

extern "C" void kernel_launch(void* const* d_in, const int* in_sizes, int n_in,
                              void* d_out, int out_size, void* d_ws, size_t ws_size,
                              hipStream_t stream) {
  const float* x = (const float*)d_in[0];
  const float* a = (const float*)d_in[1];
  const float* p = (const float*)d_in[2];
  float* out = (float*)d_out;

  char* ws = (char*)d_ws;
  u16* xb  = (u16*)(ws);                                  // 8 MiB
  u16* pab = (u16*)(ws + (size_t)8 * 1024 * 1024);        // 16 MiB
  float* x2  = (float*)(ws + (size_t)24 * 1024 * 1024);   // stats
  float* p2  = x2 + Bdim;
  float* pa  = p2 + Cdim;
  float* ani = pa + Cdim;

  prep_all<<<Bdim + Cdim, 256, 0, stream>>>(x, a, p, xb, pab, x2, p2, pa, ani);
  gemm_ep<<<dim3(64, 32), 256, 0, stream>>>(xb, pab, x2, p2, pa, ani, out);
}